// Round 7
// baseline (674.156 us; speedup 1.0000x reference)
//
#include <hip/hip_runtime.h>

#define NWG   512
#define NTHR  256
#define F     59
#define K0    29
#define NB    15
#define BROWS 131072
#define LSTR  61   // LDS row stride for final kernel (gcd(61,32)=1)
#define NSLC  8    // sliced fp64 accumulators: one 64B line per (feature,slice)

// d_ws layout: acc[NB][F][NSLC][8] doubles, then hT[F][BROWS] floats
#define ACC_PER_LAYER (F * NSLC * 8)            // 3776 doubles / layer
#define ACC_TOTAL     (NB * ACC_PER_LAYER)      // 56640 doubles = 453120 B
#define HT_OFF_B      ((size_t)ACC_TOTAL * 8)

// ---------------------------------------------------------------------------
// Finalize previous layer's stats (fp64) into LDS scale/shift (f32).
// Runs redundantly in every block; acc_prev complete by stream order.
// ---------------------------------------------------------------------------
__device__ __forceinline__ void make_scsh(const double* __restrict__ acc_prev,
                                          const float* __restrict__ g,
                                          const float* __restrict__ bt,
                                          float* scsh, int tid)
{
  if (tid < F) {
    double s1 = 0.0, s2 = 0.0;
    #pragma unroll
    for (int s = 0; s < NSLC; ++s) {
      const double* slot = acc_prev + (size_t)(tid * NSLC + s) * 8;
      s1 += slot[0];
      s2 += slot[1];
    }
    const double inv = 1.0 / (double)BROWS;
    double mu   = s1 * inv;
    double var  = fma(s2, inv, -mu * mu);        // biased variance, fp64
    double rstd = 1.0 / sqrt(var + 1e-5);
    double sc   = rstd * (double)g[tid];
    scsh[tid]      = (float)sc;
    scsh[64 + tid] = (float)fma(-mu, sc, (double)bt[tid]);
  }
  __syncthreads();
}

// ---------------------------------------------------------------------------
// Wave-level stats: butterfly-reduce (sum, sumsq) of y across 64 lanes;
// lane j keeps the result for feature j in registers.
// ---------------------------------------------------------------------------
__device__ __forceinline__ void wave_stat(float y, int j, int lane,
                                          float& ms, float& mss)
{
  float s = y, ss = y * y;
  #pragma unroll
  for (int m = 1; m < 64; m <<= 1) {
    s  += __shfl_xor(s,  m, 64);
    ss += __shfl_xor(ss, m, 64);
  }
  if (lane == j) { ms = s; mss = ss; }   // -> v_cndmask, no divergence cost
}

// ---------------------------------------------------------------------------
// One Linear+ReLU layer, fp32 value path, row-per-thread, transposed h [F][B].
// No ybuf: stats reduced in-register per wave (fp32) -> tiny LDS (fp64 from
// here) -> sliced f64 atomics. One barrier after make_scsh, one before combine.
// In-place safe: h row fully read into regs before any store (value deps).
// ---------------------------------------------------------------------------
template<int K, bool FIRST>
__global__ void __launch_bounds__(NTHR)
layer_kernel(const float* in, const float* __restrict__ W,
             const float* __restrict__ bvec,
             const double* __restrict__ acc_prev,    // prev stats (unless FIRST)
             const float* __restrict__ g_prev, const float* __restrict__ bt_prev,
             float* hout, double* acc)
{
  __shared__ float scsh[128];
  __shared__ float part_s[4 * 64];
  __shared__ float part_ss[4 * 64];
  __shared__ float xbuf[FIRST ? NTHR * K0 : 1];   // x staging, FIRST only

  const int tid   = threadIdx.x;
  const int lane  = tid & 63;
  const int wid   = tid >> 6;
  const int row   = blockIdx.x * NTHR + tid;
  const int slice = blockIdx.x & (NSLC - 1);

  if (!FIRST) make_scsh(acc_prev, g_prev, bt_prev, scsh, tid);

  // ---- input row -> registers (normalized unless FIRST) ----
  float h[K];
  if (FIRST) {
    const float* xblk = in + (size_t)blockIdx.x * NTHR * K;
    #pragma unroll 4
    for (int i = tid; i < NTHR * K; i += NTHR) xbuf[i] = xblk[i];
    __syncthreads();
    #pragma unroll
    for (int k = 0; k < K; ++k) h[k] = xbuf[tid * K + k];
  } else {
    #pragma unroll
    for (int k = 0; k < K; ++k)
      h[k] = fmaf(in[(size_t)k * BROWS + row], scsh[k], scsh[64 + k]);
  }

  float ms = 0.f, mss = 0.f;      // this lane's (sum, sumsq) for feature==lane
  float* orow = hout + row;

  // ---- Linear + ReLU + store + wave stats, runtime j-loop (I$-friendly) ----
  #pragma unroll 1
  for (int j0 = 0; j0 < 56; j0 += 4) {
    const float* wp = W + j0 * K;
    float a0 = bvec[j0], a1 = bvec[j0 + 1], a2 = bvec[j0 + 2], a3 = bvec[j0 + 3];
    #pragma unroll
    for (int k = 0; k < K; ++k) {
      float hk = h[k];
      a0 = fmaf(hk, wp[k],         a0);
      a1 = fmaf(hk, wp[K + k],     a1);
      a2 = fmaf(hk, wp[2 * K + k], a2);
      a3 = fmaf(hk, wp[3 * K + k], a3);
    }
    a0 = fmaxf(a0, 0.f); a1 = fmaxf(a1, 0.f);
    a2 = fmaxf(a2, 0.f); a3 = fmaxf(a3, 0.f);
    float* op = orow + (size_t)j0 * BROWS;
    op[0]                 = a0;     // lane-consecutive: coalesced
    op[(size_t)BROWS]     = a1;
    op[(size_t)2 * BROWS] = a2;
    op[(size_t)3 * BROWS] = a3;
    wave_stat(a0, j0,     lane, ms, mss);
    wave_stat(a1, j0 + 1, lane, ms, mss);
    wave_stat(a2, j0 + 2, lane, ms, mss);
    wave_stat(a3, j0 + 3, lane, ms, mss);
  }
  { // tail j = 56..58
    const float* wp = W + 56 * K;
    float a0 = bvec[56], a1 = bvec[57], a2 = bvec[58];
    #pragma unroll
    for (int k = 0; k < K; ++k) {
      float hk = h[k];
      a0 = fmaf(hk, wp[k],         a0);
      a1 = fmaf(hk, wp[K + k],     a1);
      a2 = fmaf(hk, wp[2 * K + k], a2);
    }
    a0 = fmaxf(a0, 0.f); a1 = fmaxf(a1, 0.f); a2 = fmaxf(a2, 0.f);
    float* op = orow + (size_t)56 * BROWS;
    op[0]                 = a0;
    op[(size_t)BROWS]     = a1;
    op[(size_t)2 * BROWS] = a2;
    wave_stat(a0, 56, lane, ms, mss);
    wave_stat(a1, 57, lane, ms, mss);
    wave_stat(a2, 58, lane, ms, mss);
  }

  // ---- block combine (fp64) + sliced global atomics ----
  part_s [wid * 64 + lane] = ms;
  part_ss[wid * 64 + lane] = mss;
  __syncthreads();

  if (tid < F) {
    double t1 = (double)part_s[tid]  + (double)part_s[64 + tid] +
                (double)part_s[128 + tid] + (double)part_s[192 + tid];
    double t2 = (double)part_ss[tid] + (double)part_ss[64 + tid] +
                (double)part_ss[128 + tid] + (double)part_ss[192 + tid];
    double* slot = acc + (size_t)(tid * NSLC + slice) * 8;
    atomicAdd(slot,     t1);             // hw f64 atomic, device scope
    atomicAdd(slot + 1, t2);
  }
}

// ---------------------------------------------------------------------------
// Final BN from transposed hT -> row-major out (coalesced both sides via LDS).
// ---------------------------------------------------------------------------
__global__ void __launch_bounds__(NTHR)
final_tr_kernel(const float* __restrict__ hT, const double* __restrict__ acc_last,
                const float* __restrict__ g, const float* __restrict__ bt,
                float* __restrict__ out)
{
  __shared__ float ybuf[NTHR * LSTR];
  __shared__ float scsh[128];
  const int tid = threadIdx.x;
  make_scsh(acc_last, g, bt, scsh, tid);

  const int row = blockIdx.x * NTHR + tid;
  #pragma unroll
  for (int j = 0; j < F; ++j)
    ybuf[tid * LSTR + j] = fmaf(hT[(size_t)j * BROWS + row], scsh[j], scsh[64 + j]);
  __syncthreads();

  float* oblk = out + (size_t)blockIdx.x * NTHR * F;
  #pragma unroll 4
  for (int i = tid; i < NTHR * F; i += NTHR)
    oblk[i] = ybuf[(i / F) * LSTR + (i % F)];
}

// ---------------------------------------------------------------------------
extern "C" void kernel_launch(void* const* d_in, const int* in_sizes, int n_in,
                              void* d_out, int out_size, void* d_ws, size_t ws_size,
                              hipStream_t stream)
{
  const float* x   = (const float*)d_in[0];
  const float* W0  = (const float*)d_in[1];
  const float* b0  = (const float*)d_in[2];
  const float* g0  = (const float*)d_in[3];
  const float* bt0 = (const float*)d_in[4];
  const float* Ws  = (const float*)d_in[5];
  const float* bs  = (const float*)d_in[6];
  const float* gs  = (const float*)d_in[7];
  const float* bts = (const float*)d_in[8];
  float* out = (float*)d_out;

  double* acc = (double*)d_ws;               // [NB][F][NSLC][8]
  float*  hT  = (float*)((char*)d_ws + HT_OFF_B);   // [F][BROWS]

  // zero the atomic accumulators every call (deterministic, capture-safe)
  hipMemsetAsync(d_ws, 0, (size_t)ACC_TOTAL * sizeof(double), stream);

  // layer 0: x[B,29] -> hT[59][B]
  layer_kernel<K0, true><<<NWG, NTHR, 0, stream>>>(
      x, W0, b0, nullptr, nullptr, nullptr, hT, acc);

  // layers 1..14: in-place transposed, normalize-prev-on-read
  for (int b = 1; b < NB; ++b) {
    const float* gp  = (b == 1) ? g0  : gs  + (size_t)(b - 2) * F;
    const float* btp = (b == 1) ? bt0 : bts + (size_t)(b - 2) * F;
    layer_kernel<F, false><<<NWG, NTHR, 0, stream>>>(
        hT, Ws + (size_t)(b - 1) * F * F, bs + (size_t)(b - 1) * F,
        acc + (size_t)(b - 1) * ACC_PER_LAYER, gp, btp,
        hT, acc + (size_t)b * ACC_PER_LAYER);
  }

  // apply layer 14's BN: hT -> row-major d_out
  final_tr_kernel<<<NWG, NTHR, 0, stream>>>(
      hT, acc + (size_t)(NB - 1) * ACC_PER_LAYER,
      gs + (size_t)(NB - 2) * F, bts + (size_t)(NB - 2) * F, out);
}